// Round 9
// baseline (128.577 us; speedup 1.0000x reference)
//
#include <hip/hip_runtime.h>

// ---------------------------------------------------------------------------
// BatchRelationalModule: b=16, c=64, L=256, F=64
// Factorization: layer0 pre-act = A[b,q,f] + B'[b,p,f]  (B' has bg0 folded in)
// Round 9: R8 structure, but f32->bf16 via SAFE software round-half-up pack
// (int bias + hi16 pack, ~5 VALU/pair) -- the R8 v_cvt_pk_bf16_f32 asm
// produced garbage (un-probed semantics). No exotic instructions.
// ---------------------------------------------------------------------------

typedef short s8v __attribute__((ext_vector_type(8)));     // 8 x bf16 (4 VGPR)
typedef short s4v __attribute__((ext_vector_type(4)));     // 4 x bf16 (2 VGPR)
typedef float f4v __attribute__((ext_vector_type(4)));     // 4 x f32  (4 VGPR)
typedef unsigned u4v __attribute__((ext_vector_type(4)));
typedef unsigned u2v __attribute__((ext_vector_type(2)));

#define KEEP(x) asm volatile("" : "+v"(x))   // opaque: forbids remat/sink

#define MFMA16(a, b, c) __builtin_amdgcn_mfma_f32_16x16x16bf16_1k(a, b, c, 0, 0, 0)

// round-half-up f32->bf16 pair pack: (bits+0x8000) hi16s. <=0.5 ulp, no NaN/Inf
// inputs here. Plain integer ops -- compiler may fuse the pack to v_perm_b32.
__device__ __forceinline__ unsigned pkrh(float a, float b) {
  unsigned ua = __builtin_bit_cast(unsigned, a) + 0x8000u;
  unsigned ub = __builtin_bit_cast(unsigned, b) + 0x8000u;
  return (ua >> 16) | (ub & 0xFFFF0000u);
}
__device__ __forceinline__ f4v relu4(f4v v) {
  f4v z = {0.f, 0.f, 0.f, 0.f};
  return __builtin_elementwise_max(v, z);
}
__device__ __forceinline__ s8v cvt8(f4v a, f4v b) {
  u4v u = {pkrh(a[0], a[1]), pkrh(a[2], a[3]),
           pkrh(b[0], b[1]), pkrh(b[2], b[3])};
  return __builtin_bit_cast(s8v, u);
}
__device__ __forceinline__ s4v cvt4(f4v a) {
  u2v u = {pkrh(a[0], a[1]), pkrh(a[2], a[3])};
  return __builtin_bit_cast(s4v, u);
}
__device__ __forceinline__ f4v ldf4(const float* p) {
  return *(const f4v*)p;
}

// ---------------------------------------------------------------------------
// Kernel 1: precompute A and B' (fp32).
// ---------------------------------------------------------------------------
__global__ __launch_bounds__(256) void k_pre(
    const float* __restrict__ x, const float* __restrict__ Wg0,
    const float* __restrict__ bg0, float* __restrict__ Ag,
    float* __restrict__ Bg) {
  __shared__ float ws[64 * 131];
  __shared__ float xs[64 * 17];

  const int t = threadIdx.x;
  const int b = blockIdx.x >> 4;
  const int l0 = (blockIdx.x & 15) * 16;

  for (int i = t; i < 64 * 130; i += 256) {
    int f = i / 130, d = i - f * 130;
    ws[f * 131 + d] = Wg0[i];
  }
  for (int i = t; i < 64 * 16; i += 256) {
    int ch = i >> 4, li = i & 15;
    xs[ch * 17 + li] = x[b * 16384 + ch * 256 + l0 + li];
  }
  __syncthreads();

  const int f = t & 63;
  const int w = t >> 6;
  float accA[4] = {0.f, 0.f, 0.f, 0.f};
  float accB[4] = {0.f, 0.f, 0.f, 0.f};
  for (int d = 0; d < 64; ++d) {
    float wa = ws[f * 131 + d];
    float wb = ws[f * 131 + 65 + d];
#pragma unroll
    for (int i = 0; i < 4; ++i) {
      float xv = xs[d * 17 + w + 4 * i];
      accA[i] += xv * wa;
      accB[i] += xv * wb;
    }
  }
  const float wca = ws[f * 131 + 64];
  const float wcb = ws[f * 131 + 129];
  const float bias = bg0[f];
#pragma unroll
  for (int i = 0; i < 4; ++i) {
    int l = l0 + w + 4 * i;
    Ag[(b * 256 + l) * 64 + f] = accA[i] + (float)l * wca;
    Bg[(b * 256 + l) * 64 + f] = accB[i] + (float)l * wcb + bias;
  }
}

// ---------------------------------------------------------------------------
// Kernel 2: pair loop. grid (64, 16) x 256 thr, launch_bounds(256,3).
// Per p (16/block): bq via imm-offset ds_read_b128 -> X=relu(A+B') ->
// layer1 2x mfma16x16x32 (bias in C) -> relu + pkrh pack ->
// layer2 4x mfma16x16x16 direct chain -> relu -> accumulate.
// ---------------------------------------------------------------------------
__global__ __launch_bounds__(256, 3) void k_main(
    const float* __restrict__ Ag, const float* __restrict__ Bg,
    const float* __restrict__ Wg1, const float* __restrict__ bg1,
    const float* __restrict__ Wg2, const float* __restrict__ bg2,
    float* __restrict__ Part) {
  __shared__ __align__(16) float Bs[16 * 64];   // 4 KB
  __shared__ float Sblk[64];

  const int t = threadIdx.x;
  const int wid = t >> 6;
  const int lane = t & 63;
  const int mm = lane & 15;
  const int quad = lane >> 4;
  const int b = blockIdx.y;
  const int blkx = blockIdx.x;          // 0..63
  const int qq = blkx & 3;
  const int p0 = (blkx >> 2) * 16;
  const int q0 = (qq * 4 + wid) * 16;

  if (t < 64) Sblk[t] = 0.f;

  // ---- stage B'[16 rows] (4 KB) into LDS, coalesced dwordx4 ----
  {
    const f4v* Bb4 = (const f4v*)(Bg + (b * 256 + p0) * 64);
    ((f4v*)Bs)[t] = Bb4[t];
  }

  // ---- A rows pinned: A[q0+mm][f = kh*32 + quad*8 + j] ----
  const float* Arow = Ag + (b * 256 + q0 + mm) * 64;
  f4v af0 = ldf4(Arow + quad * 8);
  f4v af1 = ldf4(Arow + quad * 8 + 4);
  f4v af2 = ldf4(Arow + 32 + quad * 8);
  f4v af3 = ldf4(Arow + 36 + quad * 8);

  // ---- layer-1 weights, K32 A-operand: W1[gt*16+mm][kh*32+quad*8+j] ----
  s8v W1f[4][2];
  // ---- layer-2 weights, K16 A-operand: W2[ot*16+mm][gt*16+quad*4+i] ----
  s4v W2f[4][4];
  f4v c1i[4], c2i[4];
#pragma unroll
  for (int gt = 0; gt < 4; ++gt) {
    c1i[gt] = ldf4(bg1 + gt * 16 + quad * 4);
    c2i[gt] = ldf4(bg2 + gt * 16 + quad * 4);
#pragma unroll
    for (int kh = 0; kh < 2; ++kh) {
      const float* r1 = Wg1 + (gt * 16 + mm) * 64 + kh * 32 + quad * 8;
      W1f[gt][kh] = cvt8(ldf4(r1), ldf4(r1 + 4));
    }
#pragma unroll
    for (int kt = 0; kt < 4; ++kt) {
      const float* r2 = Wg2 + (gt * 16 + mm) * 64 + kt * 16 + quad * 4;
      W2f[gt][kt] = cvt4(ldf4(r2));
    }
  }
  // Pin loop-invariants in registers (defeat remat/sink).
#pragma unroll
  for (int gt = 0; gt < 4; ++gt) {
    KEEP(W1f[gt][0]); KEEP(W1f[gt][1]);
    KEEP(W2f[gt][0]); KEEP(W2f[gt][1]); KEEP(W2f[gt][2]); KEEP(W2f[gt][3]);
    KEEP(c1i[gt]); KEEP(c2i[gt]);
  }
  KEEP(af0); KEEP(af1); KEEP(af2); KEEP(af3);

  __syncthreads();   // Bs staged + Sblk zeroed

  f4v cs[4] = {{0.f,0.f,0.f,0.f},{0.f,0.f,0.f,0.f},
               {0.f,0.f,0.f,0.f},{0.f,0.f,0.f,0.f}};

#pragma unroll 4
  for (int ip = 0; ip < 16; ++ip) {
    // ---- B'-frag: quad-broadcast ds_read_b128, immediate offsets ----
    const float* brow = Bs + ip * 64;
    f4v bq0 = ldf4(brow + quad * 8);
    f4v bq1 = ldf4(brow + quad * 8 + 4);
    f4v bq2 = ldf4(brow + 32 + quad * 8);
    f4v bq3 = ldf4(brow + 36 + quad * 8);

    // ---- X fragment: X[q=mm][f] = relu(A+B'), K32 A/B-operand layout ----
    s8v x0 = cvt8(relu4(af0 + bq0), relu4(af1 + bq1));
    s8v x1 = cvt8(relu4(af2 + bq2), relu4(af3 + bq3));

    // ---- layer 1 + direct layer 2 (no LDS between) ----
    s4v pk[4];
#pragma unroll
    for (int gt = 0; gt < 4; ++gt) {
      f4v a = c1i[gt];
      a = __builtin_amdgcn_mfma_f32_16x16x32_bf16(W1f[gt][0], x0, a, 0, 0, 0);
      a = __builtin_amdgcn_mfma_f32_16x16x32_bf16(W1f[gt][1], x1, a, 0, 0, 0);
      // lane: Y1[g=gt*16+quad*4+r][q=mm] == K16 B-operand frag (k=quad*4+i, n=mm)
      pk[gt] = cvt4(relu4(a));
    }
#pragma unroll
    for (int ot = 0; ot < 4; ++ot) {
      f4v a = c2i[ot];
      a = MFMA16(W2f[ot][0], pk[0], a);
      a = MFMA16(W2f[ot][1], pk[1], a);
      a = MFMA16(W2f[ot][2], pk[2], a);
      a = MFMA16(W2f[ot][3], pk[3], a);
      cs[ot] += relu4(a);    // lane: o = ot*16+quad*4+r, q = mm
    }
  }

  // ---- reduce over q (mm lanes) -> Sblk (LDS) -> distinct global slot ----
#pragma unroll
  for (int ot = 0; ot < 4; ++ot) {
#pragma unroll
    for (int r = 0; r < 4; ++r) {
      float v = cs[ot][r];
      v += __shfl_xor(v, 1);
      v += __shfl_xor(v, 2);
      v += __shfl_xor(v, 4);
      v += __shfl_xor(v, 8);
      if (mm == 0) atomicAdd(&Sblk[ot * 16 + quad * 4 + r], v);  // LDS only
    }
  }
  __syncthreads();
  if (t < 64) Part[(b * 64 + blkx) * 64 + t] = Sblk[t];   // no contention
}

// ---------------------------------------------------------------------------
// Kernel 3: reduce 64 partials per (b,o), then f-network. grid 16 x 64.
// ---------------------------------------------------------------------------
__global__ __launch_bounds__(64) void k_final(
    const float* __restrict__ Part, const float* __restrict__ Wp,
    const float* __restrict__ bp, const float* __restrict__ Wo,
    const float* __restrict__ bo, float* __restrict__ out) {
  __shared__ float sv[64], tv[64];
  const int b = blockIdx.x, t = threadIdx.x;
  float s = 0.f;
  const float* Pb = Part + b * 64 * 64;
#pragma unroll
  for (int j = 0; j < 64; ++j) s += Pb[j * 64 + t];   // coalesced rows
  sv[t] = s;
  __syncthreads();
  float acc = bp[t];
  for (int g = 0; g < 64; ++g) acc += sv[g] * Wp[t * 64 + g];
  tv[t] = fmaxf(acc, 0.f);
  __syncthreads();
  float o = bo[t];
  for (int f = 0; f < 64; ++f) o += tv[f] * Wo[t * 64 + f];
  out[b * 64 + t] = o;
}

// ---------------------------------------------------------------------------
extern "C" void kernel_launch(void* const* d_in, const int* in_sizes, int n_in,
                              void* d_out, int out_size, void* d_ws, size_t ws_size,
                              hipStream_t stream) {
  const float* x   = (const float*)d_in[0];
  const float* Wg0 = (const float*)d_in[1];
  const float* bg0 = (const float*)d_in[2];
  const float* Wg1 = (const float*)d_in[3];
  const float* bg1 = (const float*)d_in[4];
  const float* Wg2 = (const float*)d_in[5];
  const float* bg2 = (const float*)d_in[6];
  const float* Wp  = (const float*)d_in[7];
  const float* bp  = (const float*)d_in[8];
  const float* Wo  = (const float*)d_in[9];
  const float* bo  = (const float*)d_in[10];
  float* out = (float*)d_out;

  float* Ag   = (float*)d_ws;            // [16][256][64] fp32 = 1 MB
  float* Bg   = Ag + 16 * 256 * 64;      // [16][256][64] fp32 = 1 MB
  float* Part = Bg + 16 * 256 * 64;      // [16][64][64] fp32 = 256 KB

  k_pre<<<256, 256, 0, stream>>>(x, Wg0, bg0, Ag, Bg);
  k_main<<<dim3(64, 16), 256, 0, stream>>>(Ag, Bg, Wg1, bg1, Wg2, bg2, Part);
  k_final<<<16, 64, 0, stream>>>(Part, Wp, bp, Wo, bo, out);
}

// Round 10
// 120.261 us; speedup vs baseline: 1.0691x; 1.0691x over previous
//
#include <hip/hip_runtime.h>

// ---------------------------------------------------------------------------
// BatchRelationalModule: b=16, c=64, L=256, F=64
// Factorization: layer0 pre-act = A[b,q,f] + B'[b,p,f]  (B' has bg0 folded in)
// Round 10: R7 config (512 blocks, 32 p/block, bounds(256,1) -- best measured
// 45.1 us) + TWO p per iteration as independent dependency chains (intra-wave
// ILP against the ds_read->MFMA-chain latency that R7/R9's 2-4 waves/SIMD
// cannot hide) + pkrh pack + atomic-free epilogue.
// ---------------------------------------------------------------------------

typedef short s8v __attribute__((ext_vector_type(8)));     // 8 x bf16 (4 VGPR)
typedef short s4v __attribute__((ext_vector_type(4)));     // 4 x bf16 (2 VGPR)
typedef float f4v __attribute__((ext_vector_type(4)));     // 4 x f32  (4 VGPR)
typedef unsigned u4v __attribute__((ext_vector_type(4)));
typedef unsigned u2v __attribute__((ext_vector_type(2)));

#define KEEP(x) asm volatile("" : "+v"(x))   // opaque: forbids remat/sink

#define MFMA32(a, b, c) __builtin_amdgcn_mfma_f32_16x16x32_bf16(a, b, c, 0, 0, 0)
#define MFMA16(a, b, c) __builtin_amdgcn_mfma_f32_16x16x16bf16_1k(a, b, c, 0, 0, 0)

// round-half-up f32->bf16 pair pack: (bits+0x8000) hi16s. <=0.5 ulp here.
__device__ __forceinline__ unsigned pkrh(float a, float b) {
  unsigned ua = __builtin_bit_cast(unsigned, a) + 0x8000u;
  unsigned ub = __builtin_bit_cast(unsigned, b) + 0x8000u;
  return (ua >> 16) | (ub & 0xFFFF0000u);
}
__device__ __forceinline__ f4v relu4(f4v v) {
  f4v z = {0.f, 0.f, 0.f, 0.f};
  return __builtin_elementwise_max(v, z);
}
__device__ __forceinline__ s8v cvt8(f4v a, f4v b) {
  u4v u = {pkrh(a[0], a[1]), pkrh(a[2], a[3]),
           pkrh(b[0], b[1]), pkrh(b[2], b[3])};
  return __builtin_bit_cast(s8v, u);
}
__device__ __forceinline__ s4v cvt4(f4v a) {
  u2v u = {pkrh(a[0], a[1]), pkrh(a[2], a[3])};
  return __builtin_bit_cast(s4v, u);
}
__device__ __forceinline__ f4v ldf4(const float* p) {
  return *(const f4v*)p;
}

// ---------------------------------------------------------------------------
// Kernel 1: precompute A and B' (fp32).
// ---------------------------------------------------------------------------
__global__ __launch_bounds__(256) void k_pre(
    const float* __restrict__ x, const float* __restrict__ Wg0,
    const float* __restrict__ bg0, float* __restrict__ Ag,
    float* __restrict__ Bg) {
  __shared__ float ws[64 * 131];
  __shared__ float xs[64 * 17];

  const int t = threadIdx.x;
  const int b = blockIdx.x >> 4;
  const int l0 = (blockIdx.x & 15) * 16;

  for (int i = t; i < 64 * 130; i += 256) {
    int f = i / 130, d = i - f * 130;
    ws[f * 131 + d] = Wg0[i];
  }
  for (int i = t; i < 64 * 16; i += 256) {
    int ch = i >> 4, li = i & 15;
    xs[ch * 17 + li] = x[b * 16384 + ch * 256 + l0 + li];
  }
  __syncthreads();

  const int f = t & 63;
  const int w = t >> 6;
  float accA[4] = {0.f, 0.f, 0.f, 0.f};
  float accB[4] = {0.f, 0.f, 0.f, 0.f};
  for (int d = 0; d < 64; ++d) {
    float wa = ws[f * 131 + d];
    float wb = ws[f * 131 + 65 + d];
#pragma unroll
    for (int i = 0; i < 4; ++i) {
      float xv = xs[d * 17 + w + 4 * i];
      accA[i] += xv * wa;
      accB[i] += xv * wb;
    }
  }
  const float wca = ws[f * 131 + 64];
  const float wcb = ws[f * 131 + 129];
  const float bias = bg0[f];
#pragma unroll
  for (int i = 0; i < 4; ++i) {
    int l = l0 + w + 4 * i;
    Ag[(b * 256 + l) * 64 + f] = accA[i] + (float)l * wca;
    Bg[(b * 256 + l) * 64 + f] = accB[i] + (float)l * wcb + bias;
  }
}

// ---------------------------------------------------------------------------
// Kernel 2: pair loop. grid (32, 16) x 256 thr, bounds(256,1).
// 32 p/block staged in LDS; inner loop handles p and p+1 as two INDEPENDENT
// chains (2x bq ds_reads in flight, 2 interleaved MFMA chains).
// ---------------------------------------------------------------------------
__global__ __launch_bounds__(256, 1) void k_main(
    const float* __restrict__ Ag, const float* __restrict__ Bg,
    const float* __restrict__ Wg1, const float* __restrict__ bg1,
    const float* __restrict__ Wg2, const float* __restrict__ bg2,
    float* __restrict__ Part) {
  __shared__ __align__(16) float Bs[32 * 64];   // 8 KB
  __shared__ float Sw[4][64];                   // per-wave partials

  const int t = threadIdx.x;
  const int wid = t >> 6;
  const int lane = t & 63;
  const int mm = lane & 15;
  const int quad = lane >> 4;
  const int b = blockIdx.y;
  const int blkx = blockIdx.x;          // 0..31
  const int qq = blkx & 3;
  const int p0 = (blkx >> 2) * 32;
  const int q0 = (qq * 4 + wid) * 16;

  // ---- stage B'[32 rows] (8 KB) into LDS, coalesced dwordx4 ----
  {
    const f4v* Bb4 = (const f4v*)(Bg + (b * 256 + p0) * 64);
    ((f4v*)Bs)[t] = Bb4[t];
    ((f4v*)Bs)[t + 256] = Bb4[t + 256];
  }

  // ---- A rows pinned: A[q0+mm][f = kh*32 + quad*8 + j] ----
  const float* Arow = Ag + (b * 256 + q0 + mm) * 64;
  f4v af0 = ldf4(Arow + quad * 8);
  f4v af1 = ldf4(Arow + quad * 8 + 4);
  f4v af2 = ldf4(Arow + 32 + quad * 8);
  f4v af3 = ldf4(Arow + 36 + quad * 8);

  // ---- layer-1 weights, K32 A-operand: W1[gt*16+mm][kh*32+quad*8+j] ----
  s8v W1f[4][2];
  // ---- layer-2 weights, K16 A-operand: W2[ot*16+mm][gt*16+quad*4+i] ----
  s4v W2f[4][4];
  f4v c1i[4], c2i[4];
#pragma unroll
  for (int gt = 0; gt < 4; ++gt) {
    c1i[gt] = ldf4(bg1 + gt * 16 + quad * 4);
    c2i[gt] = ldf4(bg2 + gt * 16 + quad * 4);
#pragma unroll
    for (int kh = 0; kh < 2; ++kh) {
      const float* r1 = Wg1 + (gt * 16 + mm) * 64 + kh * 32 + quad * 8;
      W1f[gt][kh] = cvt8(ldf4(r1), ldf4(r1 + 4));
    }
#pragma unroll
    for (int kt = 0; kt < 4; ++kt) {
      const float* r2 = Wg2 + (gt * 16 + mm) * 64 + kt * 16 + quad * 4;
      W2f[gt][kt] = cvt4(ldf4(r2));
    }
  }
  // Pin loop-invariants in registers (defeat remat/sink).
#pragma unroll
  for (int gt = 0; gt < 4; ++gt) {
    KEEP(W1f[gt][0]); KEEP(W1f[gt][1]);
    KEEP(W2f[gt][0]); KEEP(W2f[gt][1]); KEEP(W2f[gt][2]); KEEP(W2f[gt][3]);
    KEEP(c1i[gt]); KEEP(c2i[gt]);
  }
  KEEP(af0); KEEP(af1); KEEP(af2); KEEP(af3);

  __syncthreads();   // Bs staged

  f4v cs[4] = {{0.f,0.f,0.f,0.f},{0.f,0.f,0.f,0.f},
               {0.f,0.f,0.f,0.f},{0.f,0.f,0.f,0.f}};

#pragma unroll 2
  for (int ip = 0; ip < 32; ip += 2) {
    // ---- two B' rows: 8 ds_read_b128 issued together ----
    const float* brA = Bs + ip * 64;
    const float* brB = brA + 64;
    f4v a0 = ldf4(brA + quad * 8);
    f4v a1 = ldf4(brA + quad * 8 + 4);
    f4v a2 = ldf4(brA + 32 + quad * 8);
    f4v a3 = ldf4(brA + 36 + quad * 8);
    f4v b0 = ldf4(brB + quad * 8);
    f4v b1 = ldf4(brB + quad * 8 + 4);
    f4v b2 = ldf4(brB + 32 + quad * 8);
    f4v b3 = ldf4(brB + 36 + quad * 8);

    // ---- two X fragments (independent) ----
    s8v xA0 = cvt8(relu4(af0 + a0), relu4(af1 + a1));
    s8v xA1 = cvt8(relu4(af2 + a2), relu4(af3 + a3));
    s8v xB0 = cvt8(relu4(af0 + b0), relu4(af1 + b1));
    s8v xB1 = cvt8(relu4(af2 + b2), relu4(af3 + b3));

    // ---- layer 1: two interleaved independent MFMA chains ----
    s4v pkA[4], pkB[4];
#pragma unroll
    for (int gt = 0; gt < 4; ++gt) {
      f4v uA = c1i[gt];
      f4v uB = c1i[gt];
      uA = MFMA32(W1f[gt][0], xA0, uA);
      uB = MFMA32(W1f[gt][0], xB0, uB);
      uA = MFMA32(W1f[gt][1], xA1, uA);
      uB = MFMA32(W1f[gt][1], xB1, uB);
      pkA[gt] = cvt4(relu4(uA));
      pkB[gt] = cvt4(relu4(uB));
    }
    // ---- layer 2: two interleaved chains, direct K16 fragment reuse ----
#pragma unroll
    for (int ot = 0; ot < 4; ++ot) {
      f4v uA = c2i[ot];
      f4v uB = c2i[ot];
      uA = MFMA16(W2f[ot][0], pkA[0], uA);
      uB = MFMA16(W2f[ot][0], pkB[0], uB);
      uA = MFMA16(W2f[ot][1], pkA[1], uA);
      uB = MFMA16(W2f[ot][1], pkB[1], uB);
      uA = MFMA16(W2f[ot][2], pkA[2], uA);
      uB = MFMA16(W2f[ot][2], pkB[2], uB);
      uA = MFMA16(W2f[ot][3], pkA[3], uA);
      uB = MFMA16(W2f[ot][3], pkB[3], uB);
      cs[ot] += relu4(uA) + relu4(uB);
    }
  }

  // ---- per-wave partials (no atomics): Sw[wid][o] then tree-sum ----
#pragma unroll
  for (int ot = 0; ot < 4; ++ot) {
#pragma unroll
    for (int r = 0; r < 4; ++r) {
      float v = cs[ot][r];
      v += __shfl_xor(v, 1);
      v += __shfl_xor(v, 2);
      v += __shfl_xor(v, 4);
      v += __shfl_xor(v, 8);
      if (mm == 0) Sw[wid][ot * 16 + quad * 4 + r] = v;
    }
  }
  __syncthreads();
  if (t < 64)
    Part[(b * 32 + blkx) * 64 + t] =
        Sw[0][t] + Sw[1][t] + Sw[2][t] + Sw[3][t];
}

// ---------------------------------------------------------------------------
// Kernel 3: reduce 32 partials per (b,o), then f-network. grid 16 x 64.
// ---------------------------------------------------------------------------
__global__ __launch_bounds__(64) void k_final(
    const float* __restrict__ Part, const float* __restrict__ Wp,
    const float* __restrict__ bp, const float* __restrict__ Wo,
    const float* __restrict__ bo, float* __restrict__ out) {
  __shared__ float sv[64], tv[64];
  const int b = blockIdx.x, t = threadIdx.x;
  float s = 0.f;
  const float* Pb = Part + b * 32 * 64;
#pragma unroll
  for (int j = 0; j < 32; ++j) s += Pb[j * 64 + t];   // coalesced rows
  sv[t] = s;
  __syncthreads();
  float acc = bp[t];
  for (int g = 0; g < 64; ++g) acc += sv[g] * Wp[t * 64 + g];
  tv[t] = fmaxf(acc, 0.f);
  __syncthreads();
  float o = bo[t];
  for (int f = 0; f < 64; ++f) o += tv[f] * Wo[t * 64 + f];
  out[b * 64 + t] = o;
}

// ---------------------------------------------------------------------------
extern "C" void kernel_launch(void* const* d_in, const int* in_sizes, int n_in,
                              void* d_out, int out_size, void* d_ws, size_t ws_size,
                              hipStream_t stream) {
  const float* x   = (const float*)d_in[0];
  const float* Wg0 = (const float*)d_in[1];
  const float* bg0 = (const float*)d_in[2];
  const float* Wg1 = (const float*)d_in[3];
  const float* bg1 = (const float*)d_in[4];
  const float* Wg2 = (const float*)d_in[5];
  const float* bg2 = (const float*)d_in[6];
  const float* Wp  = (const float*)d_in[7];
  const float* bp  = (const float*)d_in[8];
  const float* Wo  = (const float*)d_in[9];
  const float* bo  = (const float*)d_in[10];
  float* out = (float*)d_out;

  float* Ag   = (float*)d_ws;            // [16][256][64] fp32 = 1 MB
  float* Bg   = Ag + 16 * 256 * 64;      // [16][256][64] fp32 = 1 MB
  float* Part = Bg + 16 * 256 * 64;      // [16][32][64] fp32 = 128 KB

  k_pre<<<256, 256, 0, stream>>>(x, Wg0, bg0, Ag, Bg);
  k_main<<<dim3(32, 16), 256, 0, stream>>>(Ag, Bg, Wg1, bg1, Wg2, bg2, Part);
  k_final<<<16, 64, 0, stream>>>(Part, Wp, bp, Wo, bo, out);
}